// Round 3
// baseline (179.612 us; speedup 1.0000x reference)
//
#include <hip/hip_runtime.h>

// Problem constants: B=16384, IN_DIM=1024, D=256, C=100
#define BATCH 16384
#define KDIM  1024
#define DDIM  256
#define CNUM  100
#define CPAD  112   // classes padded to multiple of 16 for MFMA

typedef __bf16 bf16x4 __attribute__((ext_vector_type(4)));
typedef __bf16 bf16x8 __attribute__((ext_vector_type(8)));
typedef float  floatx4 __attribute__((ext_vector_type(4)));

static __device__ __forceinline__ unsigned short f2b(float f) {
    return __builtin_bit_cast(unsigned short, (__bf16)f);
}

// ---------------- prep (merged): W transpose->bf16, P->bf16 + pnorm2 --------
__global__ __launch_bounds__(256) void prep(const float* __restrict__ W,
                                            const float* __restrict__ P,
                                            unsigned short* __restrict__ Wt,
                                            unsigned short* __restrict__ Pbf,
                                            float* __restrict__ pnorm2) {
    __shared__ float T[32][33];
    const int bid = blockIdx.x;
    if (bid < 256) {
        const int k0 = (bid & 31) * 32;
        const int n0 = (bid >> 5) * 32;
        const int j  = threadIdx.x & 31;
        const int i0 = threadIdx.x >> 5;
#pragma unroll
        for (int l = 0; l < 4; ++l) {
            int i = i0 + l * 8;
            T[i][j] = W[(k0 + i) * DDIM + n0 + j];
        }
        __syncthreads();
#pragma unroll
        for (int l = 0; l < 4; ++l) {
            int i = i0 + l * 8;
            Wt[(n0 + i) * KDIM + k0 + j] = f2b(T[j][i]);
        }
    } else {
        const int wave = threadIdx.x >> 6;
        const int lane = threadIdx.x & 63;
        const int c = (bid - 256) * 4 + wave;
        float s = 0.f;
#pragma unroll
        for (int jj = 0; jj < 4; ++jj) {
            int d = jj * 64 + lane;
            float v = (c < CNUM) ? P[c * DDIM + d] : 0.f;
            Pbf[c * DDIM + d] = f2b(v);
            s += v * v;
        }
#pragma unroll
        for (int m = 1; m < 64; m <<= 1) s += __shfl_xor(s, m, 64);
        if (lane == 0) pnorm2[c] = s;
    }
}

// ---------------- fused main -------------------------------------------------
// 256 blocks x 1024 threads (16 waves). BM=64, BN=256 (full N -> fused epilogue).
// Wave (rc,cc): rows rc*16..+16, cols cc*64..+64. K-loop: global->VGPR direct,
// NO LDS, NO barriers. Per k-step per wave: 2x float4 A + 4x 16B B + 4 MFMA.
// All 16 waves share a 24 KB/step working set -> L1-served reuse.
__global__ __launch_bounds__(1024, 4) void fused_main(
    const float* __restrict__ x, const float* __restrict__ bias,
    const unsigned short* __restrict__ Wt, const unsigned short* __restrict__ Pbf,
    const float* __restrict__ pnorm2, float* __restrict__ out)
{
    __shared__ unsigned short Zs[64 * 264];   // epilogue only (33.8 KB)
    __shared__ float rn2[4][64];

    const int tid  = threadIdx.x;
    const int wave = tid >> 6;
    const int lane = tid & 63;
    const int lm   = lane & 15;
    const int lq   = lane >> 4;
    const int rc   = wave & 3;    // row chunk (16 rows)
    const int cc   = wave >> 2;   // col chunk (64 cols)
    const int r0   = blockIdx.x * 64;

    const float* gA = x + (r0 + rc * 16 + lm) * KDIM + lq * 8;
    const unsigned short* gB = Wt + (cc * 64 + lm) * KDIM + lq * 8;

    floatx4 acc[4];
#pragma unroll
    for (int f = 0; f < 4; ++f) { acc[f][0]=0.f; acc[f][1]=0.f; acc[f][2]=0.f; acc[f][3]=0.f; }

    // pipeline: distance-1 prefetch, no barriers anywhere in the K-loop
    floatx4 a0 = *(const floatx4*)(gA);
    floatx4 a1 = *(const floatx4*)(gA + 4);
    bf16x8 bfr[4];
#pragma unroll
    for (int f = 0; f < 4; ++f)
        bfr[f] = *(const bf16x8*)(gB + f * 16 * KDIM);

#pragma unroll 2
    for (int kk = 0; kk < KDIM; kk += 32) {
        floatx4 na0, na1;
        bf16x8 nb[4];
        if (kk + 32 < KDIM) {
            na0 = *(const floatx4*)(gA + kk + 32);
            na1 = *(const floatx4*)(gA + kk + 36);
#pragma unroll
            for (int f = 0; f < 4; ++f)
                nb[f] = *(const bf16x8*)(gB + f * 16 * KDIM + kk + 32);
        }
        bf16x8 af;
        af[0] = (__bf16)a0[0]; af[1] = (__bf16)a0[1];
        af[2] = (__bf16)a0[2]; af[3] = (__bf16)a0[3];
        af[4] = (__bf16)a1[0]; af[5] = (__bf16)a1[1];
        af[6] = (__bf16)a1[2]; af[7] = (__bf16)a1[3];
#pragma unroll
        for (int f = 0; f < 4; ++f)
            acc[f] = __builtin_amdgcn_mfma_f32_16x16x32_bf16(af, bfr[f], acc[f], 0, 0, 0);
        a0 = na0; a1 = na1;
#pragma unroll
        for (int f = 0; f < 4; ++f) bfr[f] = nb[f];
    }

    // ---- bias (C/D: row m = lq*4+r, col n = lm) ----
#pragma unroll
    for (int f = 0; f < 4; ++f) {
        float bb = bias[cc * 64 + f * 16 + lm];
#pragma unroll
        for (int r = 0; r < 4; ++r) acc[f][r] += bb;
    }

    // ---- partial row norms over this wave's 64 cols ----
    float s0 = 0.f, s1 = 0.f, s2 = 0.f, s3 = 0.f;
#pragma unroll
    for (int f = 0; f < 4; ++f) {
        s0 += acc[f][0] * acc[f][0];
        s1 += acc[f][1] * acc[f][1];
        s2 += acc[f][2] * acc[f][2];
        s3 += acc[f][3] * acc[f][3];
    }
#pragma unroll
    for (int m = 1; m < 16; m <<= 1) {
        s0 += __shfl_xor(s0, m, 64);
        s1 += __shfl_xor(s1, m, 64);
        s2 += __shfl_xor(s2, m, 64);
        s3 += __shfl_xor(s3, m, 64);
    }
    if (lm == 0) {
        int rl = rc * 16 + lq * 4;
        rn2[cc][rl + 0] = s0;
        rn2[cc][rl + 1] = s1;
        rn2[cc][rl + 2] = s2;
        rn2[cc][rl + 3] = s3;
    }

    // ---- Z -> LDS bf16 for GEMM2 ----
#pragma unroll
    for (int f = 0; f < 4; ++f) {
        int col = cc * 64 + f * 16 + lm;
#pragma unroll
        for (int r = 0; r < 4; ++r)
            Zs[(rc * 16 + lq * 4 + r) * 264 + col] = f2b(acc[f][r]);
    }
    __syncthreads();   // the only block-wide barrier

    // ---- GEMM2: D2[class][row] = P @ Z^T, M=112 N=64 K=256 ----
    if (wave < 7) {
        floatx4 acc2[4];
#pragma unroll
        for (int nf = 0; nf < 4; ++nf) { acc2[nf][0]=0.f; acc2[nf][1]=0.f; acc2[nf][2]=0.f; acc2[nf][3]=0.f; }
        const unsigned short* gP = Pbf + (wave * 16 + lm) * DDIM + lq * 8;
#pragma unroll
        for (int ks = 0; ks < 8; ++ks) {
            bf16x8 ap = *(const bf16x8*)(gP + ks * 32);   // L2-hot
#pragma unroll
            for (int nf = 0; nf < 4; ++nf) {
                bf16x8 bz = *(const bf16x8*)&Zs[(nf * 16 + lm) * 264 + ks * 32 + lq * 8];
                acc2[nf] = __builtin_amdgcn_mfma_f32_16x16x32_bf16(ap, bz, acc2[nf], 0, 0, 0);
            }
        }
        int c0 = wave * 16 + lq * 4;
        if (c0 < CNUM) {   // tile 6: only lq==0 (classes 96..99)
            floatx4 pn = *(const floatx4*)(pnorm2 + c0);
#pragma unroll
            for (int nf = 0; nf < 4; ++nf) {
                int rl = nf * 16 + lm;
                float rn = rn2[0][rl] + rn2[1][rl] + rn2[2][rl] + rn2[3][rl];
                floatx4 o;
#pragma unroll
                for (int r = 0; r < 4; ++r)
                    o[r] = (2.f * acc2[nf][r] - rn - pn[r]) * (1.f / 256.f);
                *(floatx4*)&out[(r0 + rl) * CNUM + c0] = o;   // 16 B aligned (100%4==0)
            }
        }
    }
}

extern "C" void kernel_launch(void* const* d_in, const int* in_sizes, int n_in,
                              void* d_out, int out_size, void* d_ws, size_t ws_size,
                              hipStream_t stream) {
    const float* x = (const float*)d_in[0];
    const float* W = (const float*)d_in[1];
    const float* b = (const float*)d_in[2];
    const float* P = (const float*)d_in[3];
    float* out = (float*)d_out;

    // ws: Wt bf16 [256][1024] | Pbf bf16 [112][256] | pnorm2 fp32 [112]
    unsigned short* Wt  = (unsigned short*)d_ws;
    unsigned short* Pbf = Wt + KDIM * DDIM;
    float* pn2 = (float*)(Pbf + CPAD * DDIM);

    prep<<<256 + CPAD / 4, 256, 0, stream>>>(W, P, Wt, Pbf, pn2);
    fused_main<<<BATCH / 64, 1024, 0, stream>>>(x, b, Wt, Pbf, pn2, out);
}

// Round 4
// 124.083 us; speedup vs baseline: 1.4475x; 1.4475x over previous
//
#include <hip/hip_runtime.h>

// Problem constants: B=16384, IN_DIM=1024, D=256, C=100
#define BATCH 16384
#define KDIM  1024
#define DDIM  256
#define CNUM  100
#define CPAD  112   // classes padded to multiple of 16 for MFMA

typedef __bf16 bf16x4 __attribute__((ext_vector_type(4)));
typedef __bf16 bf16x8 __attribute__((ext_vector_type(8)));
typedef float  floatx4 __attribute__((ext_vector_type(4)));

static __device__ __forceinline__ unsigned short f2b(float f) {
    return __builtin_bit_cast(unsigned short, (__bf16)f);
}

// async global->LDS, 16B/lane; LDS dest = wave-uniform base + lane*16
static __device__ __forceinline__ void gload_lds16(const unsigned short* g,
                                                   unsigned short* l) {
    __builtin_amdgcn_global_load_lds(
        (const __attribute__((address_space(1))) unsigned int*)g,
        (__attribute__((address_space(3))) unsigned int*)l, 16, 0, 0);
}

// ---------------- prep (merged): W transpose->bf16, P->bf16 + pnorm2 --------
__global__ __launch_bounds__(256) void prep(const float* __restrict__ W,
                                            const float* __restrict__ P,
                                            unsigned short* __restrict__ Wt,
                                            unsigned short* __restrict__ Pbf,
                                            float* __restrict__ pnorm2) {
    __shared__ float T[32][33];
    const int bid = blockIdx.x;
    if (bid < 256) {
        const int k0 = (bid & 31) * 32;
        const int n0 = (bid >> 5) * 32;
        const int j  = threadIdx.x & 31;
        const int i0 = threadIdx.x >> 5;
#pragma unroll
        for (int l = 0; l < 4; ++l) {
            int i = i0 + l * 8;
            T[i][j] = W[(k0 + i) * DDIM + n0 + j];
        }
        __syncthreads();
#pragma unroll
        for (int l = 0; l < 4; ++l) {
            int i = i0 + l * 8;
            Wt[(n0 + i) * KDIM + k0 + j] = f2b(T[j][i]);
        }
    } else {
        const int wave = threadIdx.x >> 6;
        const int lane = threadIdx.x & 63;
        const int c = (bid - 256) * 4 + wave;
        float s = 0.f;
#pragma unroll
        for (int jj = 0; jj < 4; ++jj) {
            int d = jj * 64 + lane;
            float v = (c < CNUM) ? P[c * DDIM + d] : 0.f;
            Pbf[c * DDIM + d] = f2b(v);
            s += v * v;
        }
#pragma unroll
        for (int m = 1; m < 64; m <<= 1) s += __shfl_xor(s, m, 64);
        if (lane == 0) pnorm2[c] = s;
    }
}

// ---------------- fused main -------------------------------------------------
// grid 512 (BM=32), 256 thr / 4 waves. BK=64 -> 16 barrier pairs (was 32).
// Wave w: all 32 rows x cols [w*64, w*64+64). Per iter: 16 MFMA, 12 ds_read_b128.
// LDS layout XOR-swizzled: row r, k-block slot s holds global k-block s^(r&7).
// Swizzle applied on GLOBAL addresses (free), so async dest stays contiguous.
__global__ __launch_bounds__(256, 4) void fused_main(
    const float* __restrict__ x, const float* __restrict__ bias,
    const unsigned short* __restrict__ Wt, const unsigned short* __restrict__ Pbf,
    const float* __restrict__ pnorm2, float* __restrict__ out)
{
    __shared__ unsigned short U[18432];   // 36 KB: As[32][64] | Bs[256][64]
    unsigned short* As = U;
    unsigned short* Bs = U + 2048;
    unsigned short* Zs = U;               // epilogue union [32][264]
    __shared__ float rn2[4][32];

    const int tid  = threadIdx.x;
    const int wave = tid >> 6;
    const int lane = tid & 63;
    const int lm   = lane & 15;
    const int lq   = lane >> 4;
    const int r0   = blockIdx.x * 32;

    // A staging: thread -> row tid>>3 (0..31), k-block tid&7; 2 float4 + cvt
    const int rowA = tid >> 3;
    const int kbA  = tid & 7;
    const float* gA = x + (r0 + rowA) * KDIM + kbA * 8;
    const int ldsA = rowA * 64 + ((kbA ^ (rowA & 7)) * 8);

    // B staging: wave stages rows [wave*64, +64) in 8 asyncs of 8 rows each.
    // global k-block pre-swizzled: gkb = (l&7) ^ ((l>>3)&7)
    const int gkb = (lane & 7) ^ ((lane >> 3) & 7);
    const unsigned short* gB = Wt + (wave * 64 + (lane >> 3)) * KDIM + gkb * 8;
    unsigned short* ldsB = Bs + (wave * 64) * 64;

    // frag-read swizzle: slot for global k-block (kf*4+lq) at row with low3=lm&7
    const int sw0 = ((0 * 4 + lq) ^ (lm & 7)) * 8;
    const int sw1 = ((1 * 4 + lq) ^ (lm & 7)) * 8;

    floatx4 acc[2][4];
#pragma unroll
    for (int g = 0; g < 2; ++g)
#pragma unroll
        for (int f = 0; f < 4; ++f) { acc[g][f][0]=0.f; acc[g][f][1]=0.f; acc[g][f][2]=0.f; acc[g][f][3]=0.f; }

    floatx4 pa0 = *(const floatx4*)(gA);       // prefetch k-step 0
    floatx4 pa1 = *(const floatx4*)(gA + 4);

#pragma unroll 2
    for (int kk = 0; kk < KDIM; kk += 64) {
        __syncthreads();                       // prev iter frag reads done
#pragma unroll
        for (int j = 0; j < 8; ++j)            // async B tile (16 KB/block)
            gload_lds16(gB + j * 8 * KDIM + kk, ldsB + j * 8 * 64);
        bf16x8 ha;                             // A fp32->bf16 via registers
        ha[0] = (__bf16)pa0[0]; ha[1] = (__bf16)pa0[1];
        ha[2] = (__bf16)pa0[2]; ha[3] = (__bf16)pa0[3];
        ha[4] = (__bf16)pa1[0]; ha[5] = (__bf16)pa1[1];
        ha[6] = (__bf16)pa1[2]; ha[7] = (__bf16)pa1[3];
        *(bf16x8*)&As[ldsA] = ha;
        __syncthreads();                       // B async landed, A written
        if (kk + 64 < KDIM) {                  // distance-1 A prefetch
            pa0 = *(const floatx4*)(gA + kk + 64);
            pa1 = *(const floatx4*)(gA + kk + 68);
        }
#pragma unroll
        for (int kf = 0; kf < 2; ++kf) {
            const int sw = kf ? sw1 : sw0;
            bf16x8 a0 = *(const bf16x8*)&As[lm * 64 + sw];
            bf16x8 a1 = *(const bf16x8*)&As[(16 + lm) * 64 + sw];
#pragma unroll
            for (int f = 0; f < 4; ++f) {
                bf16x8 bfr = *(const bf16x8*)&Bs[(wave * 64 + f * 16 + lm) * 64 + sw];
                acc[0][f] = __builtin_amdgcn_mfma_f32_16x16x32_bf16(a0, bfr, acc[0][f], 0, 0, 0);
                acc[1][f] = __builtin_amdgcn_mfma_f32_16x16x32_bf16(a1, bfr, acc[1][f], 0, 0, 0);
            }
        }
    }

    // ---- bias (C/D: row m = rg*16 + lq*4+r, col n = wave*64 + f*16 + lm) ----
#pragma unroll
    for (int f = 0; f < 4; ++f) {
        float bb = bias[wave * 64 + f * 16 + lm];
#pragma unroll
        for (int g = 0; g < 2; ++g)
#pragma unroll
            for (int r = 0; r < 4; ++r) acc[g][f][r] += bb;
    }

    // ---- partial row norms over this wave's 64 cols ----
#pragma unroll
    for (int g = 0; g < 2; ++g) {
        float s0 = 0.f, s1 = 0.f, s2 = 0.f, s3 = 0.f;
#pragma unroll
        for (int f = 0; f < 4; ++f) {
            s0 += acc[g][f][0] * acc[g][f][0];
            s1 += acc[g][f][1] * acc[g][f][1];
            s2 += acc[g][f][2] * acc[g][f][2];
            s3 += acc[g][f][3] * acc[g][f][3];
        }
#pragma unroll
        for (int m = 1; m < 16; m <<= 1) {
            s0 += __shfl_xor(s0, m, 64);
            s1 += __shfl_xor(s1, m, 64);
            s2 += __shfl_xor(s2, m, 64);
            s3 += __shfl_xor(s3, m, 64);
        }
        if (lm == 0) {
            int rl = g * 16 + lq * 4;
            rn2[wave][rl + 0] = s0;
            rn2[wave][rl + 1] = s1;
            rn2[wave][rl + 2] = s2;
            rn2[wave][rl + 3] = s3;
        }
    }

    __syncthreads();                      // K-loop LDS reads done (union!)

    // ---- Z -> LDS bf16 for GEMM2 ----
#pragma unroll
    for (int g = 0; g < 2; ++g)
#pragma unroll
        for (int f = 0; f < 4; ++f) {
            int col = wave * 64 + f * 16 + lm;
#pragma unroll
            for (int r = 0; r < 4; ++r)
                Zs[(g * 16 + lq * 4 + r) * 264 + col] = f2b(acc[g][f][r]);
        }
    __syncthreads();

    // ---- GEMM2: D2[class][row] = P @ Z^T, M=112 N=32 K=256 ----
#pragma unroll
    for (int t = 0; t < 2; ++t) {
        const int ct = wave * 2 + t;
        if (ct < 7) {
            floatx4 acc2[2];
#pragma unroll
            for (int nf = 0; nf < 2; ++nf) { acc2[nf][0]=0.f; acc2[nf][1]=0.f; acc2[nf][2]=0.f; acc2[nf][3]=0.f; }
            const unsigned short* gP = Pbf + (ct * 16 + lm) * DDIM + lq * 8;
#pragma unroll
            for (int ks = 0; ks < 8; ++ks) {
                bf16x8 ap = *(const bf16x8*)(gP + ks * 32);   // L2-hot
#pragma unroll
                for (int nf = 0; nf < 2; ++nf) {
                    bf16x8 bz = *(const bf16x8*)&Zs[(nf * 16 + lm) * 264 + ks * 32 + lq * 8];
                    acc2[nf] = __builtin_amdgcn_mfma_f32_16x16x32_bf16(ap, bz, acc2[nf], 0, 0, 0);
                }
            }
            int c0 = ct * 16 + lq * 4;
            if (c0 < CNUM) {              // tile 6: only lq==0 (classes 96..99)
                floatx4 pn = *(const floatx4*)(pnorm2 + c0);
#pragma unroll
                for (int nf = 0; nf < 2; ++nf) {
                    int rl = nf * 16 + lm;
                    float rn = rn2[0][rl] + rn2[1][rl] + rn2[2][rl] + rn2[3][rl];
                    floatx4 o;
#pragma unroll
                    for (int r = 0; r < 4; ++r)
                        o[r] = (2.f * acc2[nf][r] - rn - pn[r]) * (1.f / 256.f);
                    *(floatx4*)&out[(r0 + rl) * CNUM + c0] = o;   // 16 B aligned
                }
            }
        }
    }
}

extern "C" void kernel_launch(void* const* d_in, const int* in_sizes, int n_in,
                              void* d_out, int out_size, void* d_ws, size_t ws_size,
                              hipStream_t stream) {
    const float* x = (const float*)d_in[0];
    const float* W = (const float*)d_in[1];
    const float* b = (const float*)d_in[2];
    const float* P = (const float*)d_in[3];
    float* out = (float*)d_out;

    // ws: Wt bf16 [256][1024] | Pbf bf16 [112][256] | pnorm2 fp32 [112]
    unsigned short* Wt  = (unsigned short*)d_ws;
    unsigned short* Pbf = Wt + KDIM * DDIM;
    float* pn2 = (float*)(Pbf + CPAD * DDIM);

    prep<<<256 + CPAD / 4, 256, 0, stream>>>(W, P, Wt, Pbf, pn2);
    fused_main<<<BATCH / 32, 256, 0, stream>>>(x, b, Wt, Pbf, pn2, out);
}

// Round 5
// 116.261 us; speedup vs baseline: 1.5449x; 1.0673x over previous
//
#include <hip/hip_runtime.h>

// Problem constants: B=16384, IN_DIM=1024, D=256, C=100
#define BATCH 16384
#define KDIM  1024
#define DDIM  256
#define CNUM  100
#define CPAD  112

typedef __bf16 bf16x4 __attribute__((ext_vector_type(4)));
typedef __bf16 bf16x8 __attribute__((ext_vector_type(8)));
typedef float  floatx4 __attribute__((ext_vector_type(4)));

static __device__ __forceinline__ unsigned short f2b(float f) {
    return __builtin_bit_cast(unsigned short, (__bf16)f);
}

// async global->LDS, 16B/lane; LDS dest = wave-uniform base + lane*16
static __device__ __forceinline__ void gload_lds16(const unsigned short* g,
                                                   unsigned short* l) {
    __builtin_amdgcn_global_load_lds(
        (const __attribute__((address_space(1))) unsigned int*)g,
        (__attribute__((address_space(3))) unsigned int*)l, 16, 0, 0);
}

// ---------------- prep: W transpose->bf16, P->bf16 + pnorm2 -----------------
__global__ __launch_bounds__(256) void prep(const float* __restrict__ W,
                                            const float* __restrict__ P,
                                            unsigned short* __restrict__ Wt,
                                            unsigned short* __restrict__ Pbf,
                                            float* __restrict__ pnorm2) {
    __shared__ float T[32][33];
    const int bid = blockIdx.x;
    if (bid < 256) {
        const int k0 = (bid & 31) * 32;
        const int n0 = (bid >> 5) * 32;
        const int j  = threadIdx.x & 31;
        const int i0 = threadIdx.x >> 5;
#pragma unroll
        for (int l = 0; l < 4; ++l) {
            int i = i0 + l * 8;
            T[i][j] = W[(k0 + i) * DDIM + n0 + j];
        }
        __syncthreads();
#pragma unroll
        for (int l = 0; l < 4; ++l) {
            int i = i0 + l * 8;
            Wt[(n0 + i) * KDIM + k0 + j] = f2b(T[j][i]);
        }
    } else {
        const int wave = threadIdx.x >> 6;
        const int lane = threadIdx.x & 63;
        const int c = (bid - 256) * 4 + wave;
        float s = 0.f;
#pragma unroll
        for (int jj = 0; jj < 4; ++jj) {
            int d = jj * 64 + lane;
            float v = (c < CNUM) ? P[c * DDIM + d] : 0.f;
            Pbf[c * DDIM + d] = f2b(v);
            s += v * v;
        }
#pragma unroll
        for (int m = 1; m < 64; m <<= 1) s += __shfl_xor(s, m, 64);
        if (lane == 0) pnorm2[c] = s;
    }
}

// ---------------- fused main -------------------------------------------------
// grid 512 (BM=32), 256 thr / 4 waves, BK=64, DOUBLE-BUFFERED LDS.
// One barrier per iter; B asyncs + A stores for iter k+1 are issued BEFORE the
// MFMA phase of iter k, so the barrier's vmcnt(0) drain is covered by compute.
// XOR-swizzled k-blocks (slot = kblk ^ (row&7)) on the global side (free).
__global__ __launch_bounds__(256, 2) void fused_main(
    const float* __restrict__ x, const float* __restrict__ bias,
    const unsigned short* __restrict__ Wt, const unsigned short* __restrict__ Pbf,
    const float* __restrict__ pnorm2, float* __restrict__ out)
{
    __shared__ unsigned short U[36864];   // 72 KB
    // layout: As0[32*64] | As1[32*64] | Bs0[256*64] | Bs1[256*64]
    unsigned short* Zs = U;               // epilogue union [32][264]
    __shared__ float rn2[4][32];

    const int tid  = threadIdx.x;
    const int wave = tid >> 6;
    const int lane = tid & 63;
    const int lm   = lane & 15;
    const int lq   = lane >> 4;
    const int r0   = blockIdx.x * 32;

    // A staging: thread -> row tid>>3, k-block tid&7
    const int rowA = tid >> 3;
    const int kbA  = tid & 7;
    const float* gA = x + (r0 + rowA) * KDIM + kbA * 8;
    const int ldsA = rowA * 64 + ((kbA ^ (rowA & 7)) * 8);

    // B staging: wave stages rows [wave*64,+64) in 8 asyncs of 8 rows
    const int gkb = (lane & 7) ^ ((lane >> 3) & 7);
    const unsigned short* gB = Wt + (wave * 64 + (lane >> 3)) * KDIM + gkb * 8;

    // frag-read swizzle
    const int sw0 = ((0 * 4 + lq) ^ (lm & 7)) * 8;
    const int sw1 = ((1 * 4 + lq) ^ (lm & 7)) * 8;

    floatx4 acc[2][4];
#pragma unroll
    for (int g = 0; g < 2; ++g)
#pragma unroll
        for (int f = 0; f < 4; ++f) { acc[g][f][0]=0.f; acc[g][f][1]=0.f; acc[g][f][2]=0.f; acc[g][f][3]=0.f; }

    // ---- prologue: fill buffer 0 with kk=0; prefetch A regs for kk=64 ----
    {
        floatx4 q0 = *(const floatx4*)(gA);
        floatx4 q1 = *(const floatx4*)(gA + 4);
#pragma unroll
        for (int j = 0; j < 8; ++j)
            gload_lds16(gB + j * 8 * KDIM, U + 4096 + (wave * 64 + j * 8) * 64);
        bf16x8 ha;
        ha[0] = (__bf16)q0[0]; ha[1] = (__bf16)q0[1];
        ha[2] = (__bf16)q0[2]; ha[3] = (__bf16)q0[3];
        ha[4] = (__bf16)q1[0]; ha[5] = (__bf16)q1[1];
        ha[6] = (__bf16)q1[2]; ha[7] = (__bf16)q1[3];
        *(bf16x8*)&U[ldsA] = ha;
    }
    floatx4 pa0 = *(const floatx4*)(gA + 64);
    floatx4 pa1 = *(const floatx4*)(gA + 68);
    __syncthreads();   // buffer 0 ready

#pragma unroll 2
    for (int kk = 0; kk < KDIM; kk += 64) {
        const int cur = (kk >> 6) & 1;
        const int nxt = cur ^ 1;
        unsigned short* As_c = U + cur * 2048;
        unsigned short* Bs_c = U + 4096 + cur * 16384;
        // ---- stage iter k+1 into buffer nxt (before compute!) ----
        if (kk + 64 < KDIM) {
            unsigned short* Bs_n = U + 4096 + nxt * 16384;
#pragma unroll
            for (int j = 0; j < 8; ++j)
                gload_lds16(gB + j * 8 * KDIM + kk + 64, Bs_n + (wave * 64 + j * 8) * 64);
            bf16x8 ha;
            ha[0] = (__bf16)pa0[0]; ha[1] = (__bf16)pa0[1];
            ha[2] = (__bf16)pa0[2]; ha[3] = (__bf16)pa0[3];
            ha[4] = (__bf16)pa1[0]; ha[5] = (__bf16)pa1[1];
            ha[6] = (__bf16)pa1[2]; ha[7] = (__bf16)pa1[3];
            *(bf16x8*)&(U + nxt * 2048)[ldsA] = ha;
            if (kk + 128 < KDIM) {          // distance-2 A global prefetch
                pa0 = *(const floatx4*)(gA + kk + 128);
                pa1 = *(const floatx4*)(gA + kk + 132);
            }
        }
        // ---- MFMA phase on buffer cur (covers the staging latency) ----
#pragma unroll
        for (int kf = 0; kf < 2; ++kf) {
            const int sw = kf ? sw1 : sw0;
            bf16x8 a0 = *(const bf16x8*)&As_c[lm * 64 + sw];
            bf16x8 a1 = *(const bf16x8*)&As_c[(16 + lm) * 64 + sw];
#pragma unroll
            for (int f = 0; f < 4; ++f) {
                bf16x8 bfr = *(const bf16x8*)&Bs_c[(wave * 64 + f * 16 + lm) * 64 + sw];
                acc[0][f] = __builtin_amdgcn_mfma_f32_16x16x32_bf16(a0, bfr, acc[0][f], 0, 0, 0);
                acc[1][f] = __builtin_amdgcn_mfma_f32_16x16x32_bf16(a1, bfr, acc[1][f], 0, 0, 0);
            }
        }
        __syncthreads();   // drains next-iter staging (covered) + releases bufs
    }

    // ---- bias ----
#pragma unroll
    for (int f = 0; f < 4; ++f) {
        float bb = bias[wave * 64 + f * 16 + lm];
#pragma unroll
        for (int g = 0; g < 2; ++g)
#pragma unroll
            for (int r = 0; r < 4; ++r) acc[g][f][r] += bb;
    }

    // ---- partial row norms over this wave's 64 cols ----
#pragma unroll
    for (int g = 0; g < 2; ++g) {
        float s0 = 0.f, s1 = 0.f, s2 = 0.f, s3 = 0.f;
#pragma unroll
        for (int f = 0; f < 4; ++f) {
            s0 += acc[g][f][0] * acc[g][f][0];
            s1 += acc[g][f][1] * acc[g][f][1];
            s2 += acc[g][f][2] * acc[g][f][2];
            s3 += acc[g][f][3] * acc[g][f][3];
        }
#pragma unroll
        for (int m = 1; m < 16; m <<= 1) {
            s0 += __shfl_xor(s0, m, 64);
            s1 += __shfl_xor(s1, m, 64);
            s2 += __shfl_xor(s2, m, 64);
            s3 += __shfl_xor(s3, m, 64);
        }
        if (lm == 0) {
            int rl = g * 16 + lq * 4;
            rn2[wave][rl + 0] = s0;
            rn2[wave][rl + 1] = s1;
            rn2[wave][rl + 2] = s2;
            rn2[wave][rl + 3] = s3;
        }
    }

    // ---- Z -> LDS bf16 for GEMM2 (loop's final barrier already passed) ----
#pragma unroll
    for (int g = 0; g < 2; ++g)
#pragma unroll
        for (int f = 0; f < 4; ++f) {
            int col = wave * 64 + f * 16 + lm;
#pragma unroll
            for (int r = 0; r < 4; ++r)
                Zs[(g * 16 + lq * 4 + r) * 264 + col] = f2b(acc[g][f][r]);
        }
    __syncthreads();

    // ---- GEMM2: D2[class][row] = P @ Z^T, M=112 N=32 K=256 ----
#pragma unroll
    for (int t = 0; t < 2; ++t) {
        const int ct = wave * 2 + t;
        if (ct < 7) {
            floatx4 acc2[2];
#pragma unroll
            for (int nf = 0; nf < 2; ++nf) { acc2[nf][0]=0.f; acc2[nf][1]=0.f; acc2[nf][2]=0.f; acc2[nf][3]=0.f; }
            const unsigned short* gP = Pbf + (ct * 16 + lm) * DDIM + lq * 8;
#pragma unroll
            for (int ks = 0; ks < 8; ++ks) {
                bf16x8 ap = *(const bf16x8*)(gP + ks * 32);   // L2-hot
#pragma unroll
                for (int nf = 0; nf < 2; ++nf) {
                    bf16x8 bz = *(const bf16x8*)&Zs[(nf * 16 + lm) * 264 + ks * 32 + lq * 8];
                    acc2[nf] = __builtin_amdgcn_mfma_f32_16x16x32_bf16(ap, bz, acc2[nf], 0, 0, 0);
                }
            }
            int c0 = ct * 16 + lq * 4;
            if (c0 < CNUM) {
                floatx4 pn = *(const floatx4*)(pnorm2 + c0);
#pragma unroll
                for (int nf = 0; nf < 2; ++nf) {
                    int rl = nf * 16 + lm;
                    float rn = rn2[0][rl] + rn2[1][rl] + rn2[2][rl] + rn2[3][rl];
                    floatx4 o;
#pragma unroll
                    for (int r = 0; r < 4; ++r)
                        o[r] = (2.f * acc2[nf][r] - rn - pn[r]) * (1.f / 256.f);
                    *(floatx4*)&out[(r0 + rl) * CNUM + c0] = o;
                }
            }
        }
    }
}

extern "C" void kernel_launch(void* const* d_in, const int* in_sizes, int n_in,
                              void* d_out, int out_size, void* d_ws, size_t ws_size,
                              hipStream_t stream) {
    const float* x = (const float*)d_in[0];
    const float* W = (const float*)d_in[1];
    const float* b = (const float*)d_in[2];
    const float* P = (const float*)d_in[3];
    float* out = (float*)d_out;

    unsigned short* Wt  = (unsigned short*)d_ws;
    unsigned short* Pbf = Wt + KDIM * DDIM;
    float* pn2 = (float*)(Pbf + CPAD * DDIM);

    prep<<<256 + CPAD / 4, 256, 0, stream>>>(W, P, Wt, Pbf, pn2);
    fused_main<<<BATCH / 32, 256, 0, stream>>>(x, b, Wt, Pbf, pn2, out);
}